// Round 7
// baseline (1557.498 us; speedup 1.0000x reference)
//
#include <hip/hip_runtime.h>

#define NU 100000
#define NT 200000
#define D 64
#define NLAYERS 3
#define NNZ_TOTAL 3200000
#define ALPHA 0.2f
#define NBUCKET 391      // ceil(NT / 512)
#define BSHIFT 9         // 512 rows per bucket
#define CHUNK 4096       // elements per block in binning kernels

typedef unsigned short ushort_t;

__device__ __forceinline__ float bf2f(ushort_t h) {
    return __uint_as_float((unsigned)h << 16);
}
__device__ __forceinline__ ushort_t f2bf(float x) {
    unsigned u = __float_as_uint(x);
    u += 0x7FFF + ((u >> 16) & 1);          // round-to-nearest-even
    return (ushort_t)(u >> 16);
}

// ---------------- fused init + stage-0 dot (E stored bf16; dot in fp32) ----------------
__global__ __launch_bounds__(256) void init_dot_kernel(
    const float* __restrict__ ut, const float* __restrict__ it,
    const int* __restrict__ uidx, const int* __restrict__ iidx,
    ushort_t* __restrict__ E, float* __restrict__ out)
{
    int w = (blockIdx.x * 256 + threadIdx.x) >> 6;   // user index
    int lane = threadIdx.x & 63;
    if (w >= NU) return;
    float eu = ut[uidx[w] * D + lane];
    float ei = it[iidx[w] * D + lane];
    E[w * D + lane] = f2bf(eu);
    E[(NU + w) * D + lane] = f2bf(ei);
    float p = eu * ei;
#pragma unroll
    for (int off = 32; off > 0; off >>= 1) p += __shfl_xor(p, off);
    if (lane == 0) out[w] = p;
}

// ---------------- CSR build: two-level binning ----------------
__global__ __launch_bounds__(256) void bucket_hist_kernel(const int* __restrict__ rows,
                                                          int* __restrict__ bcnt)
{
    __shared__ int l[NBUCKET];
    int t = threadIdx.x;
    for (int k = t; k < NBUCKET; k += 256) l[k] = 0;
    __syncthreads();
    int base = blockIdx.x * CHUNK;
#pragma unroll
    for (int q = 0; q < 16; ++q) {
        int i = base + q * 256 + t;
        if (i < NNZ_TOTAL) atomicAdd(&l[rows[i] >> BSHIFT], 1);
    }
    __syncthreads();
    for (int k = t; k < NBUCKET; k += 256) if (l[k]) atomicAdd(&bcnt[k], l[k]);
}

__global__ __launch_bounds__(512) void scan_buckets_kernel(const int* __restrict__ bcnt,
                                                           int* __restrict__ bstart,
                                                           int* __restrict__ bcur)
{
    __shared__ int s[512];
    int t = threadIdx.x;
    int v = (t < NBUCKET) ? bcnt[t] : 0;
    s[t] = v; __syncthreads();
    for (int off = 1; off < 512; off <<= 1) {
        int x = (t >= off) ? s[t - off] : 0;
        __syncthreads();
        s[t] += x;
        __syncthreads();
    }
    if (t < NBUCKET) { bstart[t] = s[t] - v; bcur[t] = s[t] - v; }
    if (t == 511) bstart[NBUCKET] = s[511];
}

// bin into bucket-major order; pk = (b<<22)|(rank<<10)|rowlow9
__global__ __launch_bounds__(256) void bin_kernel(
    const int* __restrict__ rows, const int* __restrict__ cols,
    const float* __restrict__ vals, int* __restrict__ bcur,
    int2* __restrict__ binned)
{
    __shared__ int lcount[NBUCKET];
    __shared__ int lbase[NBUCKET];
    int t = threadIdx.x;
    for (int k = t; k < NBUCKET; k += 256) lcount[k] = 0;
    __syncthreads();
    int base = blockIdx.x * CHUNK;
    int pk[16];
#pragma unroll
    for (int q = 0; q < 16; ++q) {
        int i = base + q * 256 + t;
        pk[q] = 0;
        if (i < NNZ_TOTAL) {
            int r = rows[i];
            int b = r >> BSHIFT;                        // < 391 (9 bits)
            int rank = atomicAdd(&lcount[b], 1);        // < 4096 (12 bits)
            pk[q] = (b << 22) | (rank << 10) | (r & 511);
        }
    }
    __syncthreads();
    for (int k = t; k < NBUCKET; k += 256)
        if (lcount[k]) lbase[k] = atomicAdd(&bcur[k], lcount[k]);
    __syncthreads();
#pragma unroll
    for (int q = 0; q < 16; ++q) {
        int i = base + q * 256 + t;
        if (i < NNZ_TOTAL) {
            int b    = (pk[q] >> 22) & 0x1FF;
            int rank = (pk[q] >> 10) & 0xFFF;
            int rl   =  pk[q] & 0x1FF;
            binned[lbase[b] + rank] =
                make_int2((rl << 18) | cols[i], __float_as_int(vals[i]));
        }
    }
}

// per-bucket scatter: builds row_ptr (512-row LDS count+scan) + final CSR;
// random writes confined to a 64KB L2-resident window.
__global__ __launch_bounds__(256) void scatter2_kernel(
    const int2* __restrict__ binned, const int* __restrict__ bstart,
    int* __restrict__ row_ptr, int2* __restrict__ csr)
{
    __shared__ int lbuf[512];
    __shared__ int aux[256];
    int b = blockIdx.x, t = threadIdx.x;
    int rowbase = b << BSHIFT;
    int nrows = min(512, NT - rowbase);
    int beg = bstart[b], end = bstart[b + 1];
    for (int k = t; k < 512; k += 256) lbuf[k] = 0;
    __syncthreads();
    for (int i = beg + t; i < end; i += 256)
        atomicAdd(&lbuf[binned[i].x >> 18], 1);
    __syncthreads();
    int c0 = lbuf[t * 2], c1 = lbuf[t * 2 + 1];
    int s = c0 + c1;
    aux[t] = s; __syncthreads();
    for (int off = 1; off < 256; off <<= 1) {
        int x = (t >= off) ? aux[t - off] : 0;
        __syncthreads();
        aux[t] += x;
        __syncthreads();
    }
    int p0 = beg + aux[t] - s;                 // absolute cursor, exclusive
    int p1 = p0 + c0;
    lbuf[t * 2] = p0; lbuf[t * 2 + 1] = p1;
    if (t * 2     < nrows) row_ptr[rowbase + t * 2]     = p0;
    if (t * 2 + 1 < nrows) row_ptr[rowbase + t * 2 + 1] = p1;
    if (t == 0) row_ptr[rowbase + nrows] = end;
    __syncthreads();
    for (int i = beg + t; i < end; i += 256) {
        int2 p = binned[i];
        int pos = atomicAdd(&lbuf[p.x >> 18], 1);
        csr[pos] = make_int2(p.x & 0x3FFFF, p.y);
    }
}

// ---------------- SpMM: R[r] = sum val * bf2f(E[col]) ----------------
__global__ __launch_bounds__(256) void spmm_kernel(
    const ushort_t* __restrict__ E, const int* __restrict__ row_ptr,
    const int2* __restrict__ csr, float* __restrict__ R)
{
    int w = (blockIdx.x * 256 + threadIdx.x) >> 6;   // row
    int lane = threadIdx.x & 63;
    if (w >= NT) return;
    int beg = __builtin_amdgcn_readfirstlane(row_ptr[w]);
    int end = __builtin_amdgcn_readfirstlane(row_ptr[w + 1]);
    float acc = 0.f;
    int j = beg;
    for (; j + 8 <= end; j += 8) {
        int2 p[8];
#pragma unroll
        for (int q = 0; q < 8; ++q) p[q] = csr[j + q];
        float ev[8];
#pragma unroll
        for (int q = 0; q < 8; ++q) ev[q] = bf2f(E[p[q].x * D + lane]);
#pragma unroll
        for (int q = 0; q < 8; ++q) acc += __int_as_float(p[q].y) * ev[q];
    }
    for (; j < end; ++j) {
        int2 p = csr[j];
        acc += __int_as_float(p.y) * bf2f(E[p.x * D + lane]);
    }
    R[w * D + lane] = acc;
}

// ---------------- fused dense + dot ----------------
// Per wave-iteration: rows (w, NU+w). Enew = lrelu(R@W1 + (R.*Eold)@W2) for
// both, stored bf16; out[w] += dot(onew_u, onew_i) in fp32.
__global__ __launch_bounds__(256) void dense_dot_kernel(
    const float* __restrict__ R, ushort_t* E,
    const float* __restrict__ W1, const float* __restrict__ W2,
    float* __restrict__ out)
{
    __shared__ float2 sAM[4][64];
    int t = threadIdx.x;
    int lane = t & 63;
    int wl = t >> 6;
    float w1r[64], w2r[64];
#pragma unroll
    for (int k = 0; k < 64; ++k) {
        w1r[k] = W1[k * 64 + lane];
        w2r[k] = W2[k * 64 + lane];
    }
#pragma unroll
    for (int k = 0; k < 64; ++k) {
        asm volatile("" : "+v"(w1r[k]), "+v"(w2r[k]));   // pin in VGPRs
    }
    int gw = blockIdx.x * 4 + wl;
    int stride = gridDim.x * 4;
    for (int w = gw; w < NU; w += stride) {
        float au = R[w * D + lane];
        float eu = bf2f(E[w * D + lane]);
        float ai = R[(NU + w) * D + lane];
        float ei = bf2f(E[(NU + w) * D + lane]);

        sAM[wl][lane] = make_float2(au, au * eu);   // wave-private, lockstep
        float ou = 0.f;
#pragma unroll
        for (int k = 0; k < 64; ++k) {
            float2 am = sAM[wl][k];
            ou += am.x * w1r[k];
            ou += am.y * w2r[k];
        }
        ou = ou > 0.f ? ou : ALPHA * ou;

        sAM[wl][lane] = make_float2(ai, ai * ei);
        float oi = 0.f;
#pragma unroll
        for (int k = 0; k < 64; ++k) {
            float2 am = sAM[wl][k];
            oi += am.x * w1r[k];
            oi += am.y * w2r[k];
        }
        oi = oi > 0.f ? oi : ALPHA * oi;

        E[w * D + lane] = f2bf(ou);
        E[(NU + w) * D + lane] = f2bf(oi);

        float p = ou * oi;
#pragma unroll
        for (int off = 32; off > 0; off >>= 1) p += __shfl_xor(p, off);
        if (lane == 0) out[w] += p;
    }
}

extern "C" void kernel_launch(void* const* d_in, const int* in_sizes, int n_in,
                              void* d_out, int out_size, void* d_ws, size_t ws_size,
                              hipStream_t stream)
{
    const float* ut   = (const float*)d_in[0];
    const float* it   = (const float*)d_in[1];
    const float* W1   = (const float*)d_in[2];
    const float* W2   = (const float*)d_in[3];
    const float* vals = (const float*)d_in[4];
    const int*   rows = (const int*)d_in[5];
    const int*   cols = (const int*)d_in[6];
    const int*   uidx = (const int*)d_in[7];
    const int*   iidx = (const int*)d_in[8];
    float* out = (float*)d_out;

    char* ws = (char*)d_ws;
    ushort_t* E    = (ushort_t*)(ws + 0);        // 25,600,000 B
    float* R       = (float*)(ws + 25600000);    // 51,200,000 B
    int2*  binned  = (int2*) R;                  // aliases R (pre-loop only)
    int*   row_ptr = (int*)  (ws + 76800000);    // 800,004 B (pad to 800,256)
    int*   bcnt    = (int*)  (ws + 77600256);    // 1,564 B (pad 2 KB)
    int*   bstart  = (int*)  (ws + 77602304);    // 1,568 B (pad 2 KB)
    int*   bcur    = (int*)  (ws + 77604352);    // 1,564 B (pad 2 KB)
    int2*  csr     = (int2*) (ws + 77606400);    // 25,600,000 B -> end 103,206,400

    hipMemsetAsync(bcnt, 0, NBUCKET * 4, stream);

    init_dot_kernel<<<NU / 4, 256, 0, stream>>>(ut, it, uidx, iidx, E, out);

    const int NBLK = (NNZ_TOTAL + CHUNK - 1) / CHUNK;   // 782
    bucket_hist_kernel<<<NBLK, 256, 0, stream>>>(rows, bcnt);
    scan_buckets_kernel<<<1, 512, 0, stream>>>(bcnt, bstart, bcur);
    bin_kernel<<<NBLK, 256, 0, stream>>>(rows, cols, vals, bcur, binned);
    scatter2_kernel<<<NBUCKET, 256, 0, stream>>>(binned, bstart, row_ptr, csr);

    for (int l = 0; l < NLAYERS; ++l) {
        spmm_kernel<<<NT / 4, 256, 0, stream>>>(E, row_ptr, csr, R);
        dense_dot_kernel<<<1536, 256, 0, stream>>>(R, E, W1 + l * 4096, W2 + l * 4096, out);
    }
}

// Round 9
// 899.514 us; speedup vs baseline: 1.7315x; 1.7315x over previous
//
#include <hip/hip_runtime.h>

#define NU 100000
#define NT 200000
#define D 64
#define NLAYERS 3
#define NNZ_TOTAL 3200000
#define ALPHA 0.2f
#define NBUCKET 391      // ceil(NT / 512)
#define BSHIFT 9         // 512 rows per bucket
#define CHUNK 4096       // elements per block in binning kernels

typedef unsigned short ushort_t;

__device__ __forceinline__ float bf2f(ushort_t h) {
    return __uint_as_float((unsigned)h << 16);
}
__device__ __forceinline__ ushort_t f2bf(float x) {
    unsigned u = __float_as_uint(x);
    u += 0x7FFF + ((u >> 16) & 1);          // round-to-nearest-even
    return (ushort_t)(u >> 16);
}

// ---------------- fused init + stage-0 dot (E stored bf16; dot in fp32) ----------------
__global__ __launch_bounds__(256) void init_dot_kernel(
    const float* __restrict__ ut, const float* __restrict__ it,
    const int* __restrict__ uidx, const int* __restrict__ iidx,
    ushort_t* __restrict__ E, float* __restrict__ out)
{
    int w = (blockIdx.x * 256 + threadIdx.x) >> 6;   // user index
    int lane = threadIdx.x & 63;
    if (w >= NU) return;
    float eu = ut[uidx[w] * D + lane];
    float ei = it[iidx[w] * D + lane];
    E[w * D + lane] = f2bf(eu);
    E[(NU + w) * D + lane] = f2bf(ei);
    float p = eu * ei;
#pragma unroll
    for (int off = 32; off > 0; off >>= 1) p += __shfl_xor(p, off);
    if (lane == 0) out[w] = p;
}

// ---------------- CSR build: two-level binning ----------------
__global__ __launch_bounds__(256) void bucket_hist_kernel(const int* __restrict__ rows,
                                                          int* __restrict__ bcnt)
{
    __shared__ int l[NBUCKET];
    int t = threadIdx.x;
    for (int k = t; k < NBUCKET; k += 256) l[k] = 0;
    __syncthreads();
    int base = blockIdx.x * CHUNK;
#pragma unroll
    for (int q = 0; q < 16; ++q) {
        int i = base + q * 256 + t;
        if (i < NNZ_TOTAL) atomicAdd(&l[rows[i] >> BSHIFT], 1);
    }
    __syncthreads();
    for (int k = t; k < NBUCKET; k += 256) if (l[k]) atomicAdd(&bcnt[k], l[k]);
}

__global__ __launch_bounds__(512) void scan_buckets_kernel(const int* __restrict__ bcnt,
                                                           int* __restrict__ bstart,
                                                           int* __restrict__ bcur)
{
    __shared__ int s[512];
    int t = threadIdx.x;
    int v = (t < NBUCKET) ? bcnt[t] : 0;
    s[t] = v; __syncthreads();
    for (int off = 1; off < 512; off <<= 1) {
        int x = (t >= off) ? s[t - off] : 0;
        __syncthreads();
        s[t] += x;
        __syncthreads();
    }
    if (t < NBUCKET) { bstart[t] = s[t] - v; bcur[t] = s[t] - v; }
    if (t == 511) bstart[NBUCKET] = s[511];
}

// bin into bucket-major order; pk = (b<<22)|(rank<<10)|rowlow9
__global__ __launch_bounds__(256) void bin_kernel(
    const int* __restrict__ rows, const int* __restrict__ cols,
    const float* __restrict__ vals, int* __restrict__ bcur,
    int2* __restrict__ binned)
{
    __shared__ int lcount[NBUCKET];
    __shared__ int lbase[NBUCKET];
    int t = threadIdx.x;
    for (int k = t; k < NBUCKET; k += 256) lcount[k] = 0;
    __syncthreads();
    int base = blockIdx.x * CHUNK;
    int pk[16];
#pragma unroll
    for (int q = 0; q < 16; ++q) {
        int i = base + q * 256 + t;
        pk[q] = 0;
        if (i < NNZ_TOTAL) {
            int r = rows[i];
            int b = r >> BSHIFT;                        // < 391 (9 bits)
            int rank = atomicAdd(&lcount[b], 1);        // < 4096 (12 bits)
            pk[q] = (b << 22) | (rank << 10) | (r & 511);
        }
    }
    __syncthreads();
    for (int k = t; k < NBUCKET; k += 256)
        if (lcount[k]) lbase[k] = atomicAdd(&bcur[k], lcount[k]);
    __syncthreads();
#pragma unroll
    for (int q = 0; q < 16; ++q) {
        int i = base + q * 256 + t;
        if (i < NNZ_TOTAL) {
            int b    = (pk[q] >> 22) & 0x1FF;
            int rank = (pk[q] >> 10) & 0xFFF;
            int rl   =  pk[q] & 0x1FF;
            binned[lbase[b] + rank] =
                make_int2((rl << 18) | cols[i], __float_as_int(vals[i]));
        }
    }
}

// per-bucket scatter: builds row_ptr (512-row LDS count+scan) + final CSR;
// random writes confined to a 64KB L2-resident window.
__global__ __launch_bounds__(256) void scatter2_kernel(
    const int2* __restrict__ binned, const int* __restrict__ bstart,
    int* __restrict__ row_ptr, int2* __restrict__ csr)
{
    __shared__ int lbuf[512];
    __shared__ int aux[256];
    int b = blockIdx.x, t = threadIdx.x;
    int rowbase = b << BSHIFT;
    int nrows = min(512, NT - rowbase);
    int beg = bstart[b], end = bstart[b + 1];
    for (int k = t; k < 512; k += 256) lbuf[k] = 0;
    __syncthreads();
    for (int i = beg + t; i < end; i += 256)
        atomicAdd(&lbuf[binned[i].x >> 18], 1);
    __syncthreads();
    int c0 = lbuf[t * 2], c1 = lbuf[t * 2 + 1];
    int s = c0 + c1;
    aux[t] = s; __syncthreads();
    for (int off = 1; off < 256; off <<= 1) {
        int x = (t >= off) ? aux[t - off] : 0;
        __syncthreads();
        aux[t] += x;
        __syncthreads();
    }
    int p0 = beg + aux[t] - s;                 // absolute cursor, exclusive
    int p1 = p0 + c0;
    lbuf[t * 2] = p0; lbuf[t * 2 + 1] = p1;
    if (t * 2     < nrows) row_ptr[rowbase + t * 2]     = p0;
    if (t * 2 + 1 < nrows) row_ptr[rowbase + t * 2 + 1] = p1;
    if (t == 0) row_ptr[rowbase + nrows] = end;
    __syncthreads();
    for (int i = beg + t; i < end; i += 256) {
        int2 p = binned[i];
        int pos = atomicAdd(&lbuf[p.x >> 18], 1);
        csr[pos] = make_int2(p.x & 0x3FFFF, p.y);
    }
}

// ---------------- SpMM: R[r] = sum val * bf2f(E[col]), R stored bf16 ----------------
__global__ __launch_bounds__(256) void spmm_kernel(
    const ushort_t* __restrict__ E, const int* __restrict__ row_ptr,
    const int2* __restrict__ csr, ushort_t* __restrict__ R)
{
    int w = (blockIdx.x * 256 + threadIdx.x) >> 6;   // row
    int lane = threadIdx.x & 63;
    if (w >= NT) return;
    int beg = __builtin_amdgcn_readfirstlane(row_ptr[w]);
    int end = __builtin_amdgcn_readfirstlane(row_ptr[w + 1]);
    float acc = 0.f;
    int j = beg;
    for (; j + 8 <= end; j += 8) {
        int2 p[8];
#pragma unroll
        for (int q = 0; q < 8; ++q) p[q] = csr[j + q];
        float ev[8];
#pragma unroll
        for (int q = 0; q < 8; ++q) ev[q] = bf2f(E[p[q].x * D + lane]);
#pragma unroll
        for (int q = 0; q < 8; ++q) acc += __int_as_float(p[q].y) * ev[q];
    }
    for (; j < end; ++j) {
        int2 p = csr[j];
        acc += __int_as_float(p.y) * bf2f(E[p.x * D + lane]);
    }
    R[w * D + lane] = f2bf(acc);
}

// ---------------- dense: E <- lrelu(R@W1 + (R.*E)@W2), in place, bf16 I/O ----------------
// One row per wave-iteration; weights pinned in VGPRs; 4-way split accumulators;
// next row's R/E prefetched before the dot loop; sA/sM separate b32 arrays.
__global__ __launch_bounds__(256) void dense_kernel(
    const ushort_t* __restrict__ R, ushort_t* E,
    const float* __restrict__ W1, const float* __restrict__ W2)
{
    __shared__ float sA[4][64];
    __shared__ float sM[4][64];
    int t = threadIdx.x;
    int lane = t & 63;
    int wl = t >> 6;
    float w1r[64], w2r[64];
#pragma unroll
    for (int k = 0; k < 64; ++k) {
        w1r[k] = W1[k * 64 + lane];
        w2r[k] = W2[k * 64 + lane];
    }
#pragma unroll
    for (int k = 0; k < 64; ++k) {
        asm volatile("" : "+v"(w1r[k]), "+v"(w2r[k]));   // pin in VGPRs
    }
    int stride = gridDim.x * 4;
    int r = blockIdx.x * 4 + wl;
    float a = 0.f, e = 0.f;
    if (r < NT) {
        a = bf2f(R[r * D + lane]);
        e = bf2f(E[r * D + lane]);
    }
    while (r < NT) {
        sA[wl][lane] = a;
        sM[wl][lane] = a * e;
        int rn = r + stride;
        float an = 0.f, en = 0.f;
        if (rn < NT) {                         // prefetch next row
            an = bf2f(R[rn * D + lane]);
            en = bf2f(E[rn * D + lane]);
        }
        float o0 = 0.f, o1 = 0.f, o2 = 0.f, o3 = 0.f;
#pragma unroll
        for (int k = 0; k < 64; k += 4) {
            o0 += sA[wl][k]     * w1r[k]     + sM[wl][k]     * w2r[k];
            o1 += sA[wl][k + 1] * w1r[k + 1] + sM[wl][k + 1] * w2r[k + 1];
            o2 += sA[wl][k + 2] * w1r[k + 2] + sM[wl][k + 2] * w2r[k + 2];
            o3 += sA[wl][k + 3] * w1r[k + 3] + sM[wl][k + 3] * w2r[k + 3];
        }
        float o = (o0 + o1) + (o2 + o3);
        o = o > 0.f ? o : ALPHA * o;
        E[r * D + lane] = f2bf(o);
        r = rn; a = an; e = en;
    }
}

// ---------------- per-stage dot: out[n] += dot(E[n], E[NU+n]) ----------------
__global__ __launch_bounds__(256) void dot_kernel(const ushort_t* __restrict__ E,
                                                  float* __restrict__ out)
{
    int w = (blockIdx.x * 256 + threadIdx.x) >> 6;   // user index
    int lane = threadIdx.x & 63;
    if (w >= NU) return;
    float p = bf2f(E[w * D + lane]) * bf2f(E[(NU + w) * D + lane]);
#pragma unroll
    for (int off = 32; off > 0; off >>= 1) p += __shfl_xor(p, off);
    if (lane == 0) out[w] += p;
}

extern "C" void kernel_launch(void* const* d_in, const int* in_sizes, int n_in,
                              void* d_out, int out_size, void* d_ws, size_t ws_size,
                              hipStream_t stream)
{
    const float* ut   = (const float*)d_in[0];
    const float* it   = (const float*)d_in[1];
    const float* W1   = (const float*)d_in[2];
    const float* W2   = (const float*)d_in[3];
    const float* vals = (const float*)d_in[4];
    const int*   rows = (const int*)d_in[5];
    const int*   cols = (const int*)d_in[6];
    const int*   uidx = (const int*)d_in[7];
    const int*   iidx = (const int*)d_in[8];
    float* out = (float*)d_out;

    char* ws = (char*)d_ws;
    ushort_t* E    = (ushort_t*)(ws + 0);        // 25,600,000 B
    ushort_t* R    = (ushort_t*)(ws + 25600000); // 25,600,000 B
    int2*  binned  = (int2*) (ws + 25600000);    // aliases R region start (pre-loop only; 25.6MB)
    int*   row_ptr = (int*)  (ws + 51200000);    // 800,004 B (pad to 800,256)
    int*   bcnt    = (int*)  (ws + 52000256);    // pad 2 KB
    int*   bstart  = (int*)  (ws + 52002304);    // pad 2 KB
    int*   bcur    = (int*)  (ws + 52004352);    // pad 2 KB
    int2*  csr     = (int2*) (ws + 52006400);    // 25,600,000 B -> end 77,606,400

    hipMemsetAsync(bcnt, 0, NBUCKET * 4, stream);

    init_dot_kernel<<<NU / 4, 256, 0, stream>>>(ut, it, uidx, iidx, E, out);

    const int NBLK = (NNZ_TOTAL + CHUNK - 1) / CHUNK;   // 782
    bucket_hist_kernel<<<NBLK, 256, 0, stream>>>(rows, bcnt);
    scan_buckets_kernel<<<1, 512, 0, stream>>>(bcnt, bstart, bcur);
    bin_kernel<<<NBLK, 256, 0, stream>>>(rows, cols, vals, bcur, binned);
    scatter2_kernel<<<NBUCKET, 256, 0, stream>>>(binned, bstart, row_ptr, csr);

    for (int l = 0; l < NLAYERS; ++l) {
        spmm_kernel<<<NT / 4, 256, 0, stream>>>(E, row_ptr, csr, R);
        dense_kernel<<<2048, 256, 0, stream>>>(R, E, W1 + l * 4096, W2 + l * 4096);
        dot_kernel<<<NU / 4, 256, 0, stream>>>(E, out);
    }
}

// Round 12
// 676.481 us; speedup vs baseline: 2.3024x; 1.3297x over previous
//
#include <hip/hip_runtime.h>

#define NU 100000
#define NT 200000
#define D 64
#define NLAYERS 3
#define NNZ_TOTAL 3200000
#define ALPHA 0.2f
#define NBUCKET 391      // ceil(NT / 512)
#define BSHIFT 9         // 512 rows per bucket
#define CHUNK 4096       // elements per block in binning kernels

typedef unsigned short ushort_t;
typedef __attribute__((ext_vector_type(8))) short bf16x8;
typedef __attribute__((ext_vector_type(4))) float f32x4;

__device__ __forceinline__ float bf2f(ushort_t h) {
    return __uint_as_float((unsigned)h << 16);
}
__device__ __forceinline__ ushort_t f2bf(float x) {
    unsigned u = __float_as_uint(x);
    u += 0x7FFF + ((u >> 16) & 1);          // round-to-nearest-even
    return (ushort_t)(u >> 16);
}

// ---------------- fused init + stage-0 dot (E stored bf16; dot in fp32) ----------------
__global__ __launch_bounds__(256) void init_dot_kernel(
    const float* __restrict__ ut, const float* __restrict__ it,
    const int* __restrict__ uidx, const int* __restrict__ iidx,
    ushort_t* __restrict__ E, float* __restrict__ out)
{
    int w = (blockIdx.x * 256 + threadIdx.x) >> 6;   // user index
    int lane = threadIdx.x & 63;
    if (w >= NU) return;
    float eu = ut[uidx[w] * D + lane];
    float ei = it[iidx[w] * D + lane];
    E[w * D + lane] = f2bf(eu);
    E[(NU + w) * D + lane] = f2bf(ei);
    float p = eu * ei;
#pragma unroll
    for (int off = 32; off > 0; off >>= 1) p += __shfl_xor(p, off);
    if (lane == 0) out[w] = p;
}

// ---------------- CSR build: two-level binning ----------------
__global__ __launch_bounds__(256) void bucket_hist_kernel(const int* __restrict__ rows,
                                                          int* __restrict__ bcnt)
{
    __shared__ int l[NBUCKET];
    int t = threadIdx.x;
    for (int k = t; k < NBUCKET; k += 256) l[k] = 0;
    __syncthreads();
    int base = blockIdx.x * CHUNK;
#pragma unroll
    for (int q = 0; q < 16; ++q) {
        int i = base + q * 256 + t;
        if (i < NNZ_TOTAL) atomicAdd(&l[rows[i] >> BSHIFT], 1);
    }
    __syncthreads();
    for (int k = t; k < NBUCKET; k += 256) if (l[k]) atomicAdd(&bcnt[k], l[k]);
}

__global__ __launch_bounds__(512) void scan_buckets_kernel(const int* __restrict__ bcnt,
                                                           int* __restrict__ bstart,
                                                           int* __restrict__ bcur)
{
    __shared__ int s[512];
    int t = threadIdx.x;
    int v = (t < NBUCKET) ? bcnt[t] : 0;
    s[t] = v; __syncthreads();
    for (int off = 1; off < 512; off <<= 1) {
        int x = (t >= off) ? s[t - off] : 0;
        __syncthreads();
        s[t] += x;
        __syncthreads();
    }
    if (t < NBUCKET) { bstart[t] = s[t] - v; bcur[t] = s[t] - v; }
    if (t == 511) bstart[NBUCKET] = s[511];
}

// bin into bucket-major order; pk = (b<<22)|(rank<<10)|rowlow9
__global__ __launch_bounds__(256) void bin_kernel(
    const int* __restrict__ rows, const int* __restrict__ cols,
    const float* __restrict__ vals, int* __restrict__ bcur,
    int2* __restrict__ binned)
{
    __shared__ int lcount[NBUCKET];
    __shared__ int lbase[NBUCKET];
    int t = threadIdx.x;
    for (int k = t; k < NBUCKET; k += 256) lcount[k] = 0;
    __syncthreads();
    int base = blockIdx.x * CHUNK;
    int pk[16];
#pragma unroll
    for (int q = 0; q < 16; ++q) {
        int i = base + q * 256 + t;
        pk[q] = 0;
        if (i < NNZ_TOTAL) {
            int r = rows[i];
            int b = r >> BSHIFT;                        // < 391 (9 bits)
            int rank = atomicAdd(&lcount[b], 1);        // < 4096 (12 bits)
            pk[q] = (b << 22) | (rank << 10) | (r & 511);
        }
    }
    __syncthreads();
    for (int k = t; k < NBUCKET; k += 256)
        if (lcount[k]) lbase[k] = atomicAdd(&bcur[k], lcount[k]);
    __syncthreads();
#pragma unroll
    for (int q = 0; q < 16; ++q) {
        int i = base + q * 256 + t;
        if (i < NNZ_TOTAL) {
            int b    = (pk[q] >> 22) & 0x1FF;
            int rank = (pk[q] >> 10) & 0xFFF;
            int rl   =  pk[q] & 0x1FF;
            binned[lbase[b] + rank] =
                make_int2((rl << 18) | cols[i], __float_as_int(vals[i]));
        }
    }
}

// per-bucket scatter: builds row_ptr (512-row LDS count+scan) + final CSR;
// random writes confined to a 64KB L2-resident window.
__global__ __launch_bounds__(256) void scatter2_kernel(
    const int2* __restrict__ binned, const int* __restrict__ bstart,
    int* __restrict__ row_ptr, int2* __restrict__ csr)
{
    __shared__ int lbuf[512];
    __shared__ int aux[256];
    int b = blockIdx.x, t = threadIdx.x;
    int rowbase = b << BSHIFT;
    int nrows = min(512, NT - rowbase);
    int beg = bstart[b], end = bstart[b + 1];
    for (int k = t; k < 512; k += 256) lbuf[k] = 0;
    __syncthreads();
    for (int i = beg + t; i < end; i += 256)
        atomicAdd(&lbuf[binned[i].x >> 18], 1);
    __syncthreads();
    int c0 = lbuf[t * 2], c1 = lbuf[t * 2 + 1];
    int s = c0 + c1;
    aux[t] = s; __syncthreads();
    for (int off = 1; off < 256; off <<= 1) {
        int x = (t >= off) ? aux[t - off] : 0;
        __syncthreads();
        aux[t] += x;
        __syncthreads();
    }
    int p0 = beg + aux[t] - s;                 // absolute cursor, exclusive
    int p1 = p0 + c0;
    lbuf[t * 2] = p0; lbuf[t * 2 + 1] = p1;
    if (t * 2     < nrows) row_ptr[rowbase + t * 2]     = p0;
    if (t * 2 + 1 < nrows) row_ptr[rowbase + t * 2 + 1] = p1;
    if (t == 0) row_ptr[rowbase + nrows] = end;
    __syncthreads();
    for (int i = beg + t; i < end; i += 256) {
        int2 p = binned[i];
        int pos = atomicAdd(&lbuf[p.x >> 18], 1);
        csr[pos] = make_int2(p.x & 0x3FFFF, p.y);
    }
}

// ---------------- SpMM: R[r] = sum val * bf2f(E[col]), R stored bf16 ----------------
__global__ __launch_bounds__(256) void spmm_kernel(
    const ushort_t* __restrict__ E, const int* __restrict__ row_ptr,
    const int2* __restrict__ csr, ushort_t* __restrict__ R)
{
    int w = (blockIdx.x * 256 + threadIdx.x) >> 6;   // row
    int lane = threadIdx.x & 63;
    if (w >= NT) return;
    int beg = __builtin_amdgcn_readfirstlane(row_ptr[w]);
    int end = __builtin_amdgcn_readfirstlane(row_ptr[w + 1]);
    float acc = 0.f;
    int j = beg;
    for (; j + 8 <= end; j += 8) {
        int2 p[8];
#pragma unroll
        for (int q = 0; q < 8; ++q) p[q] = csr[j + q];
        float ev[8];
#pragma unroll
        for (int q = 0; q < 8; ++q) ev[q] = bf2f(E[p[q].x * D + lane]);
#pragma unroll
        for (int q = 0; q < 8; ++q) acc += __int_as_float(p[q].y) * ev[q];
    }
    for (; j < end; ++j) {
        int2 p = csr[j];
        acc += __int_as_float(p.y) * bf2f(E[p.x * D + lane]);
    }
    R[w * D + lane] = f2bf(acc);
}

// ---------------- MFMA dense: E <- lrelu([R | R.*E] @ [W1;W2]) ----------------
// One bf16 GEMM, M=NT, N=64, K=128. Weights split hi+lo bf16 (2 MFMAs per
// k-step) to recover fp32 weight precision. B^T staged in LDS with XOR-swizzled
// 16B granules (~2-way conflicts). A-frags straight from global (coalesced).
__global__ __launch_bounds__(256) void mfma_dense_kernel(
    const ushort_t* __restrict__ R, ushort_t* E,
    const float* __restrict__ W1, const float* __restrict__ W2)
{
    __shared__ __align__(16) ushort_t Bt[2][64 * 128];   // [hi/lo][n][k] swizzled
    int t = threadIdx.x;
    // stage W^T as bf16 hi/lo, swizzled: granule g=k>>3 stored at g^(n&15)
    for (int idx = t; idx < 4096; idx += 256) {
        int k = idx >> 6, n = idx & 63;                  // idx = k*64+n (coalesced reads)
        float w1 = W1[idx], w2 = W2[idx];
        ushort_t h1 = f2bf(w1); ushort_t l1 = f2bf(w1 - bf2f(h1));
        ushort_t h2 = f2bf(w2); ushort_t l2 = f2bf(w2 - bf2f(h2));
        int sw1 = (k >> 3) ^ (n & 15);
        Bt[0][n * 128 + sw1 * 8 + (k & 7)] = h1;
        Bt[1][n * 128 + sw1 * 8 + (k & 7)] = l1;
        int k2 = k + 64;
        int sw2 = (k2 >> 3) ^ (n & 15);
        Bt[0][n * 128 + sw2 * 8 + (k2 & 7)] = h2;
        Bt[1][n * 128 + sw2 * 8 + (k2 & 7)] = l2;
    }
    __syncthreads();
    int lane = t & 63, wl = t >> 6;
    int sub = lane >> 4, l15 = lane & 15;
    for (int chunk = blockIdx.x; chunk < NT / 64; chunk += gridDim.x) {
        int row = chunk * 64 + wl * 16 + l15;            // A row this lane loads
        const bf16x8* Rrow = (const bf16x8*)(R + row * 64);
        const bf16x8* Erow = (const bf16x8*)(E + row * 64);
        bf16x8 a0 = Rrow[sub];          // k =      sub*8 .. +8
        bf16x8 a1 = Rrow[4 + sub];      // k = 32 + sub*8 .. +8
        bf16x8 e0 = Erow[sub];
        bf16x8 e1 = Erow[4 + sub];
        bf16x8 a2, a3;                  // gate part M = R.*E, k 64..127
#pragma unroll
        for (int j = 0; j < 8; ++j) {
            a2[j] = (short)f2bf(bf2f((ushort_t)a0[j]) * bf2f((ushort_t)e0[j]));
            a3[j] = (short)f2bf(bf2f((ushort_t)a1[j]) * bf2f((ushort_t)e1[j]));
        }
        bf16x8 afrag[4] = {a0, a1, a2, a3};
        f32x4 acc[4];
#pragma unroll
        for (int n0 = 0; n0 < 4; ++n0) acc[n0] = (f32x4){0.f, 0.f, 0.f, 0.f};
#pragma unroll
        for (int n0 = 0; n0 < 4; ++n0) {
            int n = n0 * 16 + l15;
#pragma unroll
            for (int ks = 0; ks < 4; ++ks) {
                int sw = (ks * 4 + sub) ^ (n & 15);
                bf16x8 bh = *(const bf16x8*)&Bt[0][n * 128 + sw * 8];
                bf16x8 bl = *(const bf16x8*)&Bt[1][n * 128 + sw * 8];
                acc[n0] = __builtin_amdgcn_mfma_f32_16x16x32_bf16(afrag[ks], bh, acc[n0], 0, 0, 0);
                acc[n0] = __builtin_amdgcn_mfma_f32_16x16x32_bf16(afrag[ks], bl, acc[n0], 0, 0, 0);
            }
        }
        int rowbase = chunk * 64 + wl * 16 + sub * 4;    // C: row=(lane>>4)*4+reg, col=lane&15
#pragma unroll
        for (int n0 = 0; n0 < 4; ++n0) {
#pragma unroll
            for (int reg = 0; reg < 4; ++reg) {
                float o = acc[n0][reg];
                o = o > 0.f ? o : ALPHA * o;
                E[(rowbase + reg) * 64 + n0 * 16 + l15] = f2bf(o);
            }
        }
    }
}

// ---------------- per-stage dot: out[n] += dot(E[n], E[NU+n]) ----------------
__global__ __launch_bounds__(256) void dot_kernel(const ushort_t* __restrict__ E,
                                                  float* __restrict__ out)
{
    int w = (blockIdx.x * 256 + threadIdx.x) >> 6;   // user index
    int lane = threadIdx.x & 63;
    if (w >= NU) return;
    float p = bf2f(E[w * D + lane]) * bf2f(E[(NU + w) * D + lane]);
#pragma unroll
    for (int off = 32; off > 0; off >>= 1) p += __shfl_xor(p, off);
    if (lane == 0) out[w] += p;
}

extern "C" void kernel_launch(void* const* d_in, const int* in_sizes, int n_in,
                              void* d_out, int out_size, void* d_ws, size_t ws_size,
                              hipStream_t stream)
{
    const float* ut   = (const float*)d_in[0];
    const float* it   = (const float*)d_in[1];
    const float* W1   = (const float*)d_in[2];
    const float* W2   = (const float*)d_in[3];
    const float* vals = (const float*)d_in[4];
    const int*   rows = (const int*)d_in[5];
    const int*   cols = (const int*)d_in[6];
    const int*   uidx = (const int*)d_in[7];
    const int*   iidx = (const int*)d_in[8];
    float* out = (float*)d_out;

    char* ws = (char*)d_ws;
    ushort_t* E    = (ushort_t*)(ws + 0);        // 25,600,000 B
    ushort_t* R    = (ushort_t*)(ws + 25600000); // 25,600,000 B
    int2*  binned  = (int2*) (ws + 25600000);    // aliases R region (pre-loop only)
    int*   row_ptr = (int*)  (ws + 51200000);    // 800,004 B (pad to 800,256)
    int*   bcnt    = (int*)  (ws + 52000256);    // pad 2 KB
    int*   bstart  = (int*)  (ws + 52002304);    // pad 2 KB
    int*   bcur    = (int*)  (ws + 52004352);    // pad 2 KB
    int2*  csr     = (int2*) (ws + 52006400);    // 25,600,000 B -> end 77,606,400

    hipMemsetAsync(bcnt, 0, NBUCKET * 4, stream);

    init_dot_kernel<<<NU / 4, 256, 0, stream>>>(ut, it, uidx, iidx, E, out);

    const int NBLK = (NNZ_TOTAL + CHUNK - 1) / CHUNK;   // 782
    bucket_hist_kernel<<<NBLK, 256, 0, stream>>>(rows, bcnt);
    scan_buckets_kernel<<<1, 512, 0, stream>>>(bcnt, bstart, bcur);
    bin_kernel<<<NBLK, 256, 0, stream>>>(rows, cols, vals, bcur, binned);
    scatter2_kernel<<<NBUCKET, 256, 0, stream>>>(binned, bstart, row_ptr, csr);

    for (int l = 0; l < NLAYERS; ++l) {
        spmm_kernel<<<NT / 4, 256, 0, stream>>>(E, row_ptr, csr, R);
        mfma_dense_kernel<<<1024, 256, 0, stream>>>(R, E, W1 + l * 4096, W2 + l * 4096);
        dot_kernel<<<NU / 4, 256, 0, stream>>>(E, out);
    }
}

// Round 13
// 627.865 us; speedup vs baseline: 2.4806x; 1.0774x over previous
//
#include <hip/hip_runtime.h>

#define NU 100000
#define NT 200000
#define D 64
#define NLAYERS 3
#define NNZ_TOTAL 3200000
#define ALPHA 0.2f
#define NBUCKET 391      // ceil(NT / 512)
#define BSHIFT 9         // 512 rows per bucket
#define CHUNK 4096       // elements per block in binning kernels

typedef unsigned short ushort_t;
typedef __attribute__((ext_vector_type(8))) short bf16x8;
typedef __attribute__((ext_vector_type(4))) float f32x4;

__device__ __forceinline__ float bf2f(ushort_t h) {
    return __uint_as_float((unsigned)h << 16);
}
__device__ __forceinline__ ushort_t f2bf(float x) {
    unsigned u = __float_as_uint(x);
    u += 0x7FFF + ((u >> 16) & 1);          // round-to-nearest-even
    return (ushort_t)(u >> 16);
}

// ---------------- fused init + stage-0 dot (E stored bf16; dot in fp32) ----------------
__global__ __launch_bounds__(256) void init_dot_kernel(
    const float* __restrict__ ut, const float* __restrict__ it,
    const int* __restrict__ uidx, const int* __restrict__ iidx,
    ushort_t* __restrict__ E, float* __restrict__ out)
{
    int w = (blockIdx.x * 256 + threadIdx.x) >> 6;   // user index
    int lane = threadIdx.x & 63;
    if (w >= NU) return;
    float eu = ut[uidx[w] * D + lane];
    float ei = it[iidx[w] * D + lane];
    E[w * D + lane] = f2bf(eu);
    E[(NU + w) * D + lane] = f2bf(ei);
    float p = eu * ei;
#pragma unroll
    for (int off = 32; off > 0; off >>= 1) p += __shfl_xor(p, off);
    if (lane == 0) out[w] = p;
}

// ---------------- CSR build: two-level binning ----------------
__global__ __launch_bounds__(256) void bucket_hist_kernel(const int* __restrict__ rows,
                                                          int* __restrict__ bcnt)
{
    __shared__ int l[NBUCKET];
    int t = threadIdx.x;
    for (int k = t; k < NBUCKET; k += 256) l[k] = 0;
    __syncthreads();
    int base = blockIdx.x * CHUNK;
#pragma unroll
    for (int q = 0; q < 16; ++q) {
        int i = base + q * 256 + t;
        if (i < NNZ_TOTAL) atomicAdd(&l[rows[i] >> BSHIFT], 1);
    }
    __syncthreads();
    for (int k = t; k < NBUCKET; k += 256) if (l[k]) atomicAdd(&bcnt[k], l[k]);
}

__global__ __launch_bounds__(512) void scan_buckets_kernel(const int* __restrict__ bcnt,
                                                           int* __restrict__ bstart,
                                                           int* __restrict__ bcur)
{
    __shared__ int s[512];
    int t = threadIdx.x;
    int v = (t < NBUCKET) ? bcnt[t] : 0;
    s[t] = v; __syncthreads();
    for (int off = 1; off < 512; off <<= 1) {
        int x = (t >= off) ? s[t - off] : 0;
        __syncthreads();
        s[t] += x;
        __syncthreads();
    }
    if (t < NBUCKET) { bstart[t] = s[t] - v; bcur[t] = s[t] - v; }
    if (t == 511) bstart[NBUCKET] = s[511];
}

// bin into bucket-major order; pk = (b<<22)|(rank<<10)|rowlow9
__global__ __launch_bounds__(256) void bin_kernel(
    const int* __restrict__ rows, const int* __restrict__ cols,
    const float* __restrict__ vals, int* __restrict__ bcur,
    int2* __restrict__ binned)
{
    __shared__ int lcount[NBUCKET];
    __shared__ int lbase[NBUCKET];
    int t = threadIdx.x;
    for (int k = t; k < NBUCKET; k += 256) lcount[k] = 0;
    __syncthreads();
    int base = blockIdx.x * CHUNK;
    int pk[16];
#pragma unroll
    for (int q = 0; q < 16; ++q) {
        int i = base + q * 256 + t;
        pk[q] = 0;
        if (i < NNZ_TOTAL) {
            int r = rows[i];
            int b = r >> BSHIFT;                        // < 391 (9 bits)
            int rank = atomicAdd(&lcount[b], 1);        // < 4096 (12 bits)
            pk[q] = (b << 22) | (rank << 10) | (r & 511);
        }
    }
    __syncthreads();
    for (int k = t; k < NBUCKET; k += 256)
        if (lcount[k]) lbase[k] = atomicAdd(&bcur[k], lcount[k]);
    __syncthreads();
#pragma unroll
    for (int q = 0; q < 16; ++q) {
        int i = base + q * 256 + t;
        if (i < NNZ_TOTAL) {
            int b    = (pk[q] >> 22) & 0x1FF;
            int rank = (pk[q] >> 10) & 0xFFF;
            int rl   =  pk[q] & 0x1FF;
            binned[lbase[b] + rank] =
                make_int2((rl << 18) | cols[i], __float_as_int(vals[i]));
        }
    }
}

// per-bucket scatter: builds row_ptr (512-row LDS count+scan) + final CSR;
// random writes confined to a 64KB L2-resident window.
__global__ __launch_bounds__(256) void scatter2_kernel(
    const int2* __restrict__ binned, const int* __restrict__ bstart,
    int* __restrict__ row_ptr, int2* __restrict__ csr)
{
    __shared__ int lbuf[512];
    __shared__ int aux[256];
    int b = blockIdx.x, t = threadIdx.x;
    int rowbase = b << BSHIFT;
    int nrows = min(512, NT - rowbase);
    int beg = bstart[b], end = bstart[b + 1];
    for (int k = t; k < 512; k += 256) lbuf[k] = 0;
    __syncthreads();
    for (int i = beg + t; i < end; i += 256)
        atomicAdd(&lbuf[binned[i].x >> 18], 1);
    __syncthreads();
    int c0 = lbuf[t * 2], c1 = lbuf[t * 2 + 1];
    int s = c0 + c1;
    aux[t] = s; __syncthreads();
    for (int off = 1; off < 256; off <<= 1) {
        int x = (t >= off) ? aux[t - off] : 0;
        __syncthreads();
        aux[t] += x;
        __syncthreads();
    }
    int p0 = beg + aux[t] - s;                 // absolute cursor, exclusive
    int p1 = p0 + c0;
    lbuf[t * 2] = p0; lbuf[t * 2 + 1] = p1;
    if (t * 2     < nrows) row_ptr[rowbase + t * 2]     = p0;
    if (t * 2 + 1 < nrows) row_ptr[rowbase + t * 2 + 1] = p1;
    if (t == 0) row_ptr[rowbase + nrows] = end;
    __syncthreads();
    for (int i = beg + t; i < end; i += 256) {
        int2 p = binned[i];
        int pos = atomicAdd(&lbuf[p.x >> 18], 1);
        csr[pos] = make_int2(p.x & 0x3FFFF, p.y);
    }
}

// ---------------- SpMM: R[r] = sum val * bf2f(E[col]), R stored bf16 ----------------
// 16-wide MASKED batches: every round issues 16 independent gathers (pad lanes
// read E[0] with val=0), eliminating the serial scalar tail. Row bounds are
// scalar (readfirstlane) so csr batch loads stay s_loads. csr overread (<=15
// entries past end) lands in workspace slack — safe memory, masked out.
__global__ __launch_bounds__(256) void spmm_kernel(
    const ushort_t* __restrict__ E, const int* __restrict__ row_ptr,
    const int2* __restrict__ csr, ushort_t* __restrict__ R)
{
    int w = (blockIdx.x * 256 + threadIdx.x) >> 6;   // row
    int lane = threadIdx.x & 63;
    if (w >= NT) return;
    int beg = __builtin_amdgcn_readfirstlane(row_ptr[w]);
    int end = __builtin_amdgcn_readfirstlane(row_ptr[w + 1]);
    float acc = 0.f;
    for (int j = beg; j < end; j += 16) {
        int2 p[16];
#pragma unroll
        for (int q = 0; q < 16; ++q) p[q] = csr[j + q];          // uniform addr -> s_load
        float ev[16];
#pragma unroll
        for (int q = 0; q < 16; ++q) {
            bool ok = (j + q) < end;                             // scalar predicate
            int col = ok ? p[q].x : 0;
            ev[q] = bf2f(E[col * D + lane]);
        }
#pragma unroll
        for (int q = 0; q < 16; ++q) {
            float v = ((j + q) < end) ? __int_as_float(p[q].y) : 0.f;
            acc += v * ev[q];
        }
    }
    R[w * D + lane] = f2bf(acc);
}

// ---------------- MFMA dense: E <- lrelu([R | R.*E] @ [W1;W2]) ----------------
// One bf16 GEMM, M=NT, N=64, K=128. Weights split hi+lo bf16 (2 MFMAs per
// k-step) to recover fp32 weight precision. B^T staged in LDS with XOR-swizzled
// 16B granules (~2-way conflicts). A-frags straight from global (coalesced).
__global__ __launch_bounds__(256) void mfma_dense_kernel(
    const ushort_t* __restrict__ R, ushort_t* E,
    const float* __restrict__ W1, const float* __restrict__ W2)
{
    __shared__ __align__(16) ushort_t Bt[2][64 * 128];   // [hi/lo][n][k] swizzled
    int t = threadIdx.x;
    // stage W^T as bf16 hi/lo, swizzled: granule g=k>>3 stored at g^(n&15)
    for (int idx = t; idx < 4096; idx += 256) {
        int k = idx >> 6, n = idx & 63;                  // idx = k*64+n (coalesced reads)
        float w1 = W1[idx], w2 = W2[idx];
        ushort_t h1 = f2bf(w1); ushort_t l1 = f2bf(w1 - bf2f(h1));
        ushort_t h2 = f2bf(w2); ushort_t l2 = f2bf(w2 - bf2f(h2));
        int sw1 = (k >> 3) ^ (n & 15);
        Bt[0][n * 128 + sw1 * 8 + (k & 7)] = h1;
        Bt[1][n * 128 + sw1 * 8 + (k & 7)] = l1;
        int k2 = k + 64;
        int sw2 = (k2 >> 3) ^ (n & 15);
        Bt[0][n * 128 + sw2 * 8 + (k2 & 7)] = h2;
        Bt[1][n * 128 + sw2 * 8 + (k2 & 7)] = l2;
    }
    __syncthreads();
    int lane = t & 63, wl = t >> 6;
    int sub = lane >> 4, l15 = lane & 15;
    for (int chunk = blockIdx.x; chunk < NT / 64; chunk += gridDim.x) {
        int row = chunk * 64 + wl * 16 + l15;            // A row this lane loads
        const bf16x8* Rrow = (const bf16x8*)(R + row * 64);
        const bf16x8* Erow = (const bf16x8*)(E + row * 64);
        bf16x8 a0 = Rrow[sub];          // k =      sub*8 .. +8
        bf16x8 a1 = Rrow[4 + sub];      // k = 32 + sub*8 .. +8
        bf16x8 e0 = Erow[sub];
        bf16x8 e1 = Erow[4 + sub];
        bf16x8 a2, a3;                  // gate part M = R.*E, k 64..127
#pragma unroll
        for (int j = 0; j < 8; ++j) {
            a2[j] = (short)f2bf(bf2f((ushort_t)a0[j]) * bf2f((ushort_t)e0[j]));
            a3[j] = (short)f2bf(bf2f((ushort_t)a1[j]) * bf2f((ushort_t)e1[j]));
        }
        bf16x8 afrag[4] = {a0, a1, a2, a3};
        f32x4 acc[4];
#pragma unroll
        for (int n0 = 0; n0 < 4; ++n0) acc[n0] = (f32x4){0.f, 0.f, 0.f, 0.f};
#pragma unroll
        for (int n0 = 0; n0 < 4; ++n0) {
            int n = n0 * 16 + l15;
#pragma unroll
            for (int ks = 0; ks < 4; ++ks) {
                int sw = (ks * 4 + sub) ^ (n & 15);
                bf16x8 bh = *(const bf16x8*)&Bt[0][n * 128 + sw * 8];
                bf16x8 bl = *(const bf16x8*)&Bt[1][n * 128 + sw * 8];
                acc[n0] = __builtin_amdgcn_mfma_f32_16x16x32_bf16(afrag[ks], bh, acc[n0], 0, 0, 0);
                acc[n0] = __builtin_amdgcn_mfma_f32_16x16x32_bf16(afrag[ks], bl, acc[n0], 0, 0, 0);
            }
        }
        int rowbase = chunk * 64 + wl * 16 + sub * 4;    // C: row=(lane>>4)*4+reg, col=lane&15
#pragma unroll
        for (int n0 = 0; n0 < 4; ++n0) {
#pragma unroll
            for (int reg = 0; reg < 4; ++reg) {
                float o = acc[n0][reg];
                o = o > 0.f ? o : ALPHA * o;
                E[(rowbase + reg) * 64 + n0 * 16 + l15] = f2bf(o);
            }
        }
    }
}

// ---------------- per-stage dot: out[n] += dot(E[n], E[NU+n]) ----------------
__global__ __launch_bounds__(256) void dot_kernel(const ushort_t* __restrict__ E,
                                                  float* __restrict__ out)
{
    int w = (blockIdx.x * 256 + threadIdx.x) >> 6;   // user index
    int lane = threadIdx.x & 63;
    if (w >= NU) return;
    float p = bf2f(E[w * D + lane]) * bf2f(E[(NU + w) * D + lane]);
#pragma unroll
    for (int off = 32; off > 0; off >>= 1) p += __shfl_xor(p, off);
    if (lane == 0) out[w] += p;
}

extern "C" void kernel_launch(void* const* d_in, const int* in_sizes, int n_in,
                              void* d_out, int out_size, void* d_ws, size_t ws_size,
                              hipStream_t stream)
{
    const float* ut   = (const float*)d_in[0];
    const float* it   = (const float*)d_in[1];
    const float* W1   = (const float*)d_in[2];
    const float* W2   = (const float*)d_in[3];
    const float* vals = (const float*)d_in[4];
    const int*   rows = (const int*)d_in[5];
    const int*   cols = (const int*)d_in[6];
    const int*   uidx = (const int*)d_in[7];
    const int*   iidx = (const int*)d_in[8];
    float* out = (float*)d_out;

    char* ws = (char*)d_ws;
    ushort_t* E    = (ushort_t*)(ws + 0);        // 25,600,000 B
    ushort_t* R    = (ushort_t*)(ws + 25600000); // 25,600,000 B
    int2*  binned  = (int2*) (ws + 25600000);    // aliases R region (pre-loop only)
    int*   row_ptr = (int*)  (ws + 51200000);    // 800,004 B (pad to 800,256)
    int*   bcnt    = (int*)  (ws + 52000256);    // pad 2 KB
    int*   bstart  = (int*)  (ws + 52002304);    // pad 2 KB
    int*   bcur    = (int*)  (ws + 52004352);    // pad 2 KB
    int2*  csr     = (int2*) (ws + 52006400);    // 25,600,000 B (+128B overread slack) -> 77,606,400

    hipMemsetAsync(bcnt, 0, NBUCKET * 4, stream);

    init_dot_kernel<<<NU / 4, 256, 0, stream>>>(ut, it, uidx, iidx, E, out);

    const int NBLK = (NNZ_TOTAL + CHUNK - 1) / CHUNK;   // 782
    bucket_hist_kernel<<<NBLK, 256, 0, stream>>>(rows, bcnt);
    scan_buckets_kernel<<<1, 512, 0, stream>>>(bcnt, bstart, bcur);
    bin_kernel<<<NBLK, 256, 0, stream>>>(rows, cols, vals, bcur, binned);
    scatter2_kernel<<<NBUCKET, 256, 0, stream>>>(binned, bstart, row_ptr, csr);

    for (int l = 0; l < NLAYERS; ++l) {
        spmm_kernel<<<NT / 4, 256, 0, stream>>>(E, row_ptr, csr, R);
        mfma_dense_kernel<<<1024, 256, 0, stream>>>(R, E, W1 + l * 4096, W2 + l * 4096);
        dot_kernel<<<NU / 4, 256, 0, stream>>>(E, out);
    }
}

// Round 15
// 605.507 us; speedup vs baseline: 2.5722x; 1.0369x over previous
//
#include <hip/hip_runtime.h>

#define NU 100000
#define NT 200000
#define D 64
#define NLAYERS 3
#define NNZ_TOTAL 3200000
#define ALPHA 0.2f
#define NBUCKET 391      // ceil(NT / 512)
#define BSHIFT 9         // 512 rows per bucket
#define CHUNK 2048       // elements per block in binning kernels
#define NBLK_C 1563      // ceil(NNZ_TOTAL / CHUNK)

typedef unsigned short ushort_t;
typedef __attribute__((ext_vector_type(8))) short bf16x8;
typedef __attribute__((ext_vector_type(4))) float f32x4;

__device__ __forceinline__ float bf2f(ushort_t h) {
    return __uint_as_float((unsigned)h << 16);
}
__device__ __forceinline__ ushort_t f2bf(float x) {
    unsigned u = __float_as_uint(x);
    u += 0x7FFF + ((u >> 16) & 1);          // round-to-nearest-even
    return (ushort_t)(u >> 16);
}

// ---------------- fused init + stage-0 dot (E stored bf16; dot in fp32) ----------------
__global__ __launch_bounds__(256) void init_dot_kernel(
    const float* __restrict__ ut, const float* __restrict__ it,
    const int* __restrict__ uidx, const int* __restrict__ iidx,
    ushort_t* __restrict__ E, float* __restrict__ out)
{
    int w = (blockIdx.x * 256 + threadIdx.x) >> 6;   // user index
    int lane = threadIdx.x & 63;
    if (w >= NU) return;
    float eu = ut[uidx[w] * D + lane];
    float ei = it[iidx[w] * D + lane];
    E[w * D + lane] = f2bf(eu);
    E[(NU + w) * D + lane] = f2bf(ei);
    float p = eu * ei;
#pragma unroll
    for (int off = 32; off > 0; off >>= 1) p += __shfl_xor(p, off);
    if (lane == 0) out[w] = p;
}

// ---------------- CSR build: atomic-free two-pass radix ----------------
// pass 1: per-(block,bucket) counts, no global atomics
__global__ __launch_bounds__(256) void count_kernel(const int* __restrict__ rows,
                                                    int* __restrict__ cnt)
{
    __shared__ int l[NBUCKET];
    int t = threadIdx.x, b = blockIdx.x;
    for (int k = t; k < NBUCKET; k += 256) l[k] = 0;
    __syncthreads();
    int base = b * CHUNK;
#pragma unroll
    for (int q = 0; q < 8; ++q) {
        int i = base + q * 256 + t;
        if (i < NNZ_TOTAL) atomicAdd(&l[rows[i] >> BSHIFT], 1);
    }
    __syncthreads();
    for (int k = t; k < NBUCKET; k += 256) cnt[k * NBLK_C + b] = l[k];
}

// pass 2: per-bucket exclusive scan over the 1563 block counts (in place) + totals
__global__ __launch_bounds__(256) void scan_cnt_kernel(int* __restrict__ cnt,
                                                       int* __restrict__ bcnt)
{
    __shared__ int s[256];
    int k = blockIdx.x, t = threadIdx.x;
    int carry = 0;
    for (int base = 0; base < NBLK_C; base += 256) {
        int idx = base + t;
        int v = (idx < NBLK_C) ? cnt[k * NBLK_C + idx] : 0;
        s[t] = v; __syncthreads();
        for (int off = 1; off < 256; off <<= 1) {
            int x = (t >= off) ? s[t - off] : 0;
            __syncthreads();
            s[t] += x;
            __syncthreads();
        }
        int ex = s[t] - v + carry;
        if (idx < NBLK_C) cnt[k * NBLK_C + idx] = ex;
        carry += s[255];
        __syncthreads();
    }
    if (t == 0) bcnt[k] = carry;
}

// pass 3: exclusive scan of 391 bucket totals
__global__ __launch_bounds__(512) void scan_buckets_kernel(const int* __restrict__ bcnt,
                                                           int* __restrict__ bstart)
{
    __shared__ int s[512];
    int t = threadIdx.x;
    int v = (t < NBUCKET) ? bcnt[t] : 0;
    s[t] = v; __syncthreads();
    for (int off = 1; off < 512; off <<= 1) {
        int x = (t >= off) ? s[t - off] : 0;
        __syncthreads();
        s[t] += x;
        __syncthreads();
    }
    if (t < NBUCKET) bstart[t] = s[t] - v;
    if (t == 511) bstart[NBUCKET] = s[511];
}

// pass 4: bin into bucket-major order, zero global atomics.
// pk = (bk<<20)|(rank<<9)|rowlow9  (bk<512, rank<2048, rowlow<512)
__global__ __launch_bounds__(256) void bin_kernel(
    const int* __restrict__ rows, const int* __restrict__ cols,
    const float* __restrict__ vals, const int* __restrict__ cnt,
    const int* __restrict__ bstart, int2* __restrict__ binned)
{
    __shared__ int lcount[NBUCKET];
    __shared__ int lbase[NBUCKET];
    int t = threadIdx.x, b = blockIdx.x;
    for (int k = t; k < NBUCKET; k += 256) {
        lcount[k] = 0;
        lbase[k] = bstart[k] + cnt[k * NBLK_C + b];
    }
    __syncthreads();
    int base = b * CHUNK;
    int pk[8];
#pragma unroll
    for (int q = 0; q < 8; ++q) {
        int i = base + q * 256 + t;
        pk[q] = 0;
        if (i < NNZ_TOTAL) {
            int r = rows[i];
            int bk = r >> BSHIFT;
            int rank = atomicAdd(&lcount[bk], 1);       // LDS-local only
            pk[q] = (bk << 20) | (rank << 9) | (r & 511);
        }
    }
#pragma unroll
    for (int q = 0; q < 8; ++q) {
        int i = base + q * 256 + t;
        if (i < NNZ_TOTAL) {
            int bk   = (pk[q] >> 20) & 0x1FF;
            int rank = (pk[q] >> 9) & 0x7FF;
            int rl   =  pk[q] & 0x1FF;
            binned[lbase[bk] + rank] =
                make_int2((rl << 18) | cols[i], __float_as_int(vals[i]));
        }
    }
}

// per-bucket scatter: builds row_ptr (512-row LDS count+scan) + final CSR;
// random writes confined to a 64KB L2-resident window.
__global__ __launch_bounds__(256) void scatter2_kernel(
    const int2* __restrict__ binned, const int* __restrict__ bstart,
    int* __restrict__ row_ptr, int2* __restrict__ csr)
{
    __shared__ int lbuf[512];
    __shared__ int aux[256];
    int b = blockIdx.x, t = threadIdx.x;
    int rowbase = b << BSHIFT;
    int nrows = min(512, NT - rowbase);
    int beg = bstart[b], end = bstart[b + 1];
    for (int k = t; k < 512; k += 256) lbuf[k] = 0;
    __syncthreads();
    for (int i = beg + t; i < end; i += 256)
        atomicAdd(&lbuf[binned[i].x >> 18], 1);
    __syncthreads();
    int c0 = lbuf[t * 2], c1 = lbuf[t * 2 + 1];
    int s = c0 + c1;
    aux[t] = s; __syncthreads();
    for (int off = 1; off < 256; off <<= 1) {
        int x = (t >= off) ? aux[t - off] : 0;
        __syncthreads();
        aux[t] += x;
        __syncthreads();
    }
    int p0 = beg + aux[t] - s;                 // absolute cursor, exclusive
    int p1 = p0 + c0;
    lbuf[t * 2] = p0; lbuf[t * 2 + 1] = p1;
    if (t * 2     < nrows) row_ptr[rowbase + t * 2]     = p0;
    if (t * 2 + 1 < nrows) row_ptr[rowbase + t * 2 + 1] = p1;
    if (t == 0) row_ptr[rowbase + nrows] = end;
    __syncthreads();
    for (int i = beg + t; i < end; i += 256) {
        int2 p = binned[i];
        int pos = atomicAdd(&lbuf[p.x >> 18], 1);
        csr[pos] = make_int2(p.x & 0x3FFFF, p.y);
    }
}

// ---------------- SpMM: R[r] = sum val * bf2f(E[col]), R stored bf16 ----------------
// 16-wide MASKED batches: every round issues 16 independent gathers (pad lanes
// read E[0] with val=0), eliminating the serial scalar tail.
__global__ __launch_bounds__(256) void spmm_kernel(
    const ushort_t* __restrict__ E, const int* __restrict__ row_ptr,
    const int2* __restrict__ csr, ushort_t* __restrict__ R)
{
    int w = (blockIdx.x * 256 + threadIdx.x) >> 6;   // row
    int lane = threadIdx.x & 63;
    if (w >= NT) return;
    int beg = __builtin_amdgcn_readfirstlane(row_ptr[w]);
    int end = __builtin_amdgcn_readfirstlane(row_ptr[w + 1]);
    float acc = 0.f;
    for (int j = beg; j < end; j += 16) {
        int2 p[16];
#pragma unroll
        for (int q = 0; q < 16; ++q) p[q] = csr[j + q];          // uniform addr -> s_load
        float ev[16];
#pragma unroll
        for (int q = 0; q < 16; ++q) {
            bool ok = (j + q) < end;                             // scalar predicate
            int col = ok ? p[q].x : 0;
            ev[q] = bf2f(E[col * D + lane]);
        }
#pragma unroll
        for (int q = 0; q < 16; ++q) {
            float v = ((j + q) < end) ? __int_as_float(p[q].y) : 0.f;
            acc += v * ev[q];
        }
    }
    R[w * D + lane] = f2bf(acc);
}

// ---------------- MFMA dense: E <- lrelu([R | R.*E] @ [W1;W2]) ----------------
__global__ __launch_bounds__(256) void mfma_dense_kernel(
    const ushort_t* __restrict__ R, ushort_t* E,
    const float* __restrict__ W1, const float* __restrict__ W2)
{
    __shared__ __align__(16) ushort_t Bt[2][64 * 128];   // [hi/lo][n][k] swizzled
    int t = threadIdx.x;
    for (int idx = t; idx < 4096; idx += 256) {
        int k = idx >> 6, n = idx & 63;                  // idx = k*64+n (coalesced reads)
        float w1 = W1[idx], w2 = W2[idx];
        ushort_t h1 = f2bf(w1); ushort_t l1 = f2bf(w1 - bf2f(h1));
        ushort_t h2 = f2bf(w2); ushort_t l2 = f2bf(w2 - bf2f(h2));
        int sw1 = (k >> 3) ^ (n & 15);
        Bt[0][n * 128 + sw1 * 8 + (k & 7)] = h1;
        Bt[1][n * 128 + sw1 * 8 + (k & 7)] = l1;
        int k2 = k + 64;
        int sw2 = (k2 >> 3) ^ (n & 15);
        Bt[0][n * 128 + sw2 * 8 + (k2 & 7)] = h2;
        Bt[1][n * 128 + sw2 * 8 + (k2 & 7)] = l2;
    }
    __syncthreads();
    int lane = t & 63, wl = t >> 6;
    int sub = lane >> 4, l15 = lane & 15;
    for (int chunk = blockIdx.x; chunk < NT / 64; chunk += gridDim.x) {
        int row = chunk * 64 + wl * 16 + l15;            // A row this lane loads
        const bf16x8* Rrow = (const bf16x8*)(R + row * 64);
        const bf16x8* Erow = (const bf16x8*)(E + row * 64);
        bf16x8 a0 = Rrow[sub];          // k =      sub*8 .. +8
        bf16x8 a1 = Rrow[4 + sub];      // k = 32 + sub*8 .. +8
        bf16x8 e0 = Erow[sub];
        bf16x8 e1 = Erow[4 + sub];
        bf16x8 a2, a3;                  // gate part M = R.*E, k 64..127
#pragma unroll
        for (int j = 0; j < 8; ++j) {
            a2[j] = (short)f2bf(bf2f((ushort_t)a0[j]) * bf2f((ushort_t)e0[j]));
            a3[j] = (short)f2bf(bf2f((ushort_t)a1[j]) * bf2f((ushort_t)e1[j]));
        }
        bf16x8 afrag[4] = {a0, a1, a2, a3};
        f32x4 acc[4];
#pragma unroll
        for (int n0 = 0; n0 < 4; ++n0) acc[n0] = (f32x4){0.f, 0.f, 0.f, 0.f};
#pragma unroll
        for (int n0 = 0; n0 < 4; ++n0) {
            int n = n0 * 16 + l15;
#pragma unroll
            for (int ks = 0; ks < 4; ++ks) {
                int sw = (ks * 4 + sub) ^ (n & 15);
                bf16x8 bh = *(const bf16x8*)&Bt[0][n * 128 + sw * 8];
                bf16x8 bl = *(const bf16x8*)&Bt[1][n * 128 + sw * 8];
                acc[n0] = __builtin_amdgcn_mfma_f32_16x16x32_bf16(afrag[ks], bh, acc[n0], 0, 0, 0);
                acc[n0] = __builtin_amdgcn_mfma_f32_16x16x32_bf16(afrag[ks], bl, acc[n0], 0, 0, 0);
            }
        }
        int rowbase = chunk * 64 + wl * 16 + sub * 4;    // C: row=(lane>>4)*4+reg, col=lane&15
#pragma unroll
        for (int n0 = 0; n0 < 4; ++n0) {
#pragma unroll
            for (int reg = 0; reg < 4; ++reg) {
                float o = acc[n0][reg];
                o = o > 0.f ? o : ALPHA * o;
                E[(rowbase + reg) * 64 + n0 * 16 + l15] = f2bf(o);
            }
        }
    }
}

// ---------------- per-stage dot: out[n] += dot(E[n], E[NU+n]) ----------------
__global__ __launch_bounds__(256) void dot_kernel(const ushort_t* __restrict__ E,
                                                  float* __restrict__ out)
{
    int w = (blockIdx.x * 256 + threadIdx.x) >> 6;   // user index
    int lane = threadIdx.x & 63;
    if (w >= NU) return;
    float p = bf2f(E[w * D + lane]) * bf2f(E[(NU + w) * D + lane]);
#pragma unroll
    for (int off = 32; off > 0; off >>= 1) p += __shfl_xor(p, off);
    if (lane == 0) out[w] += p;
}

extern "C" void kernel_launch(void* const* d_in, const int* in_sizes, int n_in,
                              void* d_out, int out_size, void* d_ws, size_t ws_size,
                              hipStream_t stream)
{
    const float* ut   = (const float*)d_in[0];
    const float* it   = (const float*)d_in[1];
    const float* W1   = (const float*)d_in[2];
    const float* W2   = (const float*)d_in[3];
    const float* vals = (const float*)d_in[4];
    const int*   rows = (const int*)d_in[5];
    const int*   cols = (const int*)d_in[6];
    const int*   uidx = (const int*)d_in[7];
    const int*   iidx = (const int*)d_in[8];
    float* out = (float*)d_out;

    char* ws = (char*)d_ws;
    ushort_t* E    = (ushort_t*)(ws + 0);        // 25,600,000 B
    ushort_t* R    = (ushort_t*)(ws + 25600000); // 25,600,000 B
    int2*  binned  = (int2*) (ws + 25600000);    // aliases R region (pre-loop only)
    int*   row_ptr = (int*)  (ws + 51200000);    // 800,004 B (pad to 800,256)
    int*   bcnt    = (int*)  (ws + 52000256);    // pad 2 KB
    int*   bstart  = (int*)  (ws + 52002304);    // pad 2 KB
    int2*  csr     = (int2*) (ws + 52004352);    // 25,600,000 B -> 77,604,352
    int*   cnt     = (int*)  (ws + 77604352);    // 391*1563*4 = 2,444,532 B -> ~80.05 MB

    init_dot_kernel<<<NU / 4, 256, 0, stream>>>(ut, it, uidx, iidx, E, out);

    count_kernel<<<NBLK_C, 256, 0, stream>>>(rows, cnt);
    scan_cnt_kernel<<<NBUCKET, 256, 0, stream>>>(cnt, bcnt);
    scan_buckets_kernel<<<1, 512, 0, stream>>>(bcnt, bstart);
    bin_kernel<<<NBLK_C, 256, 0, stream>>>(rows, cols, vals, cnt, bstart, binned);
    scatter2_kernel<<<NBUCKET, 256, 0, stream>>>(binned, bstart, row_ptr, csr);

    for (int l = 0; l < NLAYERS; ++l) {
        spmm_kernel<<<NT / 4, 256, 0, stream>>>(E, row_ptr, csr, R);
        mfma_dense_kernel<<<1024, 256, 0, stream>>>(R, E, W1 + l * 4096, W2 + l * 4096);
        dot_kernel<<<NU / 4, 256, 0, stream>>>(E, out);
    }
}